// Round 9
// baseline (25799.341 us; speedup 1.0000x reference)
//
#include <hip/hip_runtime.h>
#include <stdint.h>

// x: (B=4, C=64, N=8192, 1) fp32. Output edge_index int32 (2,B,N,9).
#define NB 4
#define NC 64
#define NPTS 8192
#define KK 18          // K * DILATION
#define KOUT 9         // kept after ::2
#define ROWS 32        // rows (n) per block
#define TM 64          // m-tile width (= lanes per wave)
#define NTILE (NPTS / TM)
#define PADA 68        // A-tile row stride (16B-aligned, breaks write conflicts)

// Monotone float->uint32 map (total order incl. negatives).
static __device__ __forceinline__ unsigned fkey(float d) {
    unsigned fb = __float_as_uint(d);
    fb ^= ((unsigned)((int)fb >> 31)) | 0x80000000u;
    return fb;
}

// ---------------------------------------------------------------------------
// Kernel 1 (UNCHANGED from passing round-8 version — bit-exact numpy model):
//   norm: sequential-c; pts = x/max(norm,1e-12)
//   sq: seed t0, pairwise-8 over t1..t56, sequential tail t57..t63, t0+res
// ---------------------------------------------------------------------------
__global__ __launch_bounds__(256) void normalize_kernel(
    const float* __restrict__ x, float* __restrict__ pts, float* __restrict__ sq) {
#pragma clang fp contract(off)
    int idx = blockIdx.x * 256 + threadIdx.x;   // b*NPTS + n
    if (idx >= NB * NPTS) return;
    int b = idx / NPTS, n = idx % NPTS;
    const float* xb = x + (size_t)b * NC * NPTS + n;

    float acc = 0.f;
    #pragma unroll
    for (int c = 0; c < NC; ++c) {
        float v = xb[(size_t)c * NPTS];
        acc = __fadd_rn(acc, __fmul_rn(v, v));
    }
    float nm = fmaxf(__fsqrt_rn(acc), 1e-12f);

    float t[NC];
    #pragma unroll
    for (int c = 0; c < NC; ++c) {
        float p = __fdiv_rn(xb[(size_t)c * NPTS], nm);
        pts[((size_t)b * NC + c) * NPTS + n] = p;
        t[c] = __fmul_rn(p, p);
    }
    float r[8];
    #pragma unroll
    for (int j = 0; j < 8; ++j) r[j] = t[1 + j];
    #pragma unroll
    for (int i = 8; i < 56; i += 8)
        #pragma unroll
        for (int j = 0; j < 8; ++j) r[j] = __fadd_rn(r[j], t[1 + i + j]);
    float res = __fadd_rn(__fadd_rn(__fadd_rn(r[0], r[1]), __fadd_rn(r[2], r[3])),
                          __fadd_rn(__fadd_rn(r[4], r[5]), __fadd_rn(r[6], r[7])));
    #pragma unroll
    for (int i = 57; i < NC; ++i) res = __fadd_rn(res, t[i]);
    sq[idx] = __fadd_rn(t[0], res);
}

// ---------------------------------------------------------------------------
// Kernel 2: same math (sequential-c non-FMA dot; dist=(sqa+(-2dot))+sqb;
// key=(fkey<<32)|m lower-ties), restructured for occupancy + LDS efficiency:
//   ROWS=32/block, TM=64, 4 waves; wave w owns rows 8w..8w+7, lane j owns m=j.
//   A-tile [r][c] (bcast b128 reads), B-tile [m][c] XOR-swizzled 16B chunks.
//   Staging loads prefetched into registers across the insert phase.
// ---------------------------------------------------------------------------
__global__ __launch_bounds__(256, 3) void knn_kernel(
    const float* __restrict__ pts, const float* __restrict__ sq, int* __restrict__ out) {
#pragma clang fp contract(off)
    __shared__ float sA[ROWS][PADA];                //  8.5 KB
    __shared__ float sB[TM][NC];                    // 16   KB (swizzled chunks)
    __shared__ float sSqA[ROWS];
    __shared__ unsigned long long listK[ROWS][KK];  //  4.5 KB
    __shared__ unsigned long long pendK[ROWS][TM];  // 16   KB
    __shared__ int pendCnt[ROWS];

    const int tid = threadIdx.x;
    int blk = blockIdx.x;
    // XCD-aware bijective swizzle (1024 % 8 == 0): each XCD -> 1 batch's pts.
    blk = (blk & 7) * (gridDim.x >> 3) + (blk >> 3);
    const int b    = blk >> 8;                      // 256 blocks per batch
    const int row0 = (blk & 255) * ROWS;
    const float* P  = pts + (size_t)b * NC * NPTS;
    const float* SQ = sq + b * NPTS;

    if (tid < ROWS) { sSqA[tid] = SQ[row0 + tid]; pendCnt[tid] = 0; }
    for (int i = tid; i < ROWS * KK; i += 256)
        ((unsigned long long*)listK)[i] = 0xFFFFFFFFFFFFFFFFULL;
    for (int i = tid; i < ROWS * NC; i += 256) {
        int r = i & (ROWS - 1), c = i >> 5;
        sA[r][c] = P[(size_t)c * NPTS + row0 + r];
    }
    __syncthreads();

    const int wv   = tid >> 6;        // wave id: rows 8wv..8wv+7
    const int j    = tid & 63;        // m lane
    const int swzj = j & 7;           // B-tile chunk swizzle
    float sqa[8];
    #pragma unroll
    for (int r = 0; r < 8; ++r) sqa[r] = sSqA[8 * wv + r];

    // prefetch tile 0 staging data into registers
    float4 v[4];
    float sqbv;
    {
        #pragma unroll
        for (int s = 0; s < 4; ++s) {
            const int c = (wv * 4 + s) * 4;
            v[s].x = P[(size_t)(c + 0) * NPTS + j];
            v[s].y = P[(size_t)(c + 1) * NPTS + j];
            v[s].z = P[(size_t)(c + 2) * NPTS + j];
            v[s].w = P[(size_t)(c + 3) * NPTS + j];
        }
        sqbv = SQ[j];
    }

    for (int mt = 0; mt < NTILE; ++mt) {
        const int m0 = mt * TM;
        // write staged registers to LDS (swizzled 16B chunks)
        #pragma unroll
        for (int s = 0; s < 4; ++s)
            *(float4*)&sB[j][((wv * 4 + s) ^ swzj) * 4] = v[s];
        __syncthreads();

        const float sqb = sqbv;
        // prefetch next tile while computing this one
        if (mt + 1 < NTILE) {
            const int m1 = m0 + TM;
            #pragma unroll
            for (int s = 0; s < 4; ++s) {
                const int c = (wv * 4 + s) * 4;
                v[s].x = P[(size_t)(c + 0) * NPTS + m1 + j];
                v[s].y = P[(size_t)(c + 1) * NPTS + m1 + j];
                v[s].z = P[(size_t)(c + 2) * NPTS + m1 + j];
                v[s].w = P[(size_t)(c + 3) * NPTS + m1 + j];
            }
            sqbv = SQ[m1 + j];
        }

        // dot: sequential c = 0..63 ascending, mul-round/add-round (non-FMA)
        float acc[8];
        #pragma unroll
        for (int r = 0; r < 8; ++r) acc[r] = 0.f;
        #pragma unroll
        for (int c4 = 0; c4 < 16; ++c4) {
            const float4 bv = *(const float4*)&sB[j][(c4 ^ swzj) * 4];
            #pragma unroll
            for (int r = 0; r < 8; ++r) {
                const float4 av = *(const float4*)&sA[8 * wv + r][c4 * 4];
                float a = acc[r];
                a = __fadd_rn(__fmul_rn(av.x, bv.x), a);
                a = __fadd_rn(__fmul_rn(av.y, bv.y), a);
                a = __fadd_rn(__fmul_rn(av.z, bv.z), a);
                a = __fadd_rn(__fmul_rn(av.w, bv.w), a);
                acc[r] = a;
            }
        }

        const unsigned mg = (unsigned)(m0 + j);
        #pragma unroll
        for (int r = 0; r < 8; ++r) {
            const int row = 8 * wv + r;
            const unsigned long long thr = listK[row][KK - 1];
            float d = __fadd_rn(__fadd_rn(sqa[r], __fmul_rn(-2.f, acc[r])), sqb);
            unsigned long long key = ((unsigned long long)fkey(d) << 32) | mg;
            if (key < thr) { int p = atomicAdd(&pendCnt[row], 1); pendK[row][p] = key; }
        }
        __syncthreads();

        // serial sorted insert by row owners (32 of 256 threads)
        if (tid < ROWS) {
            const int cnt = pendCnt[tid];
            for (int q = 0; q < cnt; ++q) {
                unsigned long long key = pendK[tid][q];
                if (key < listK[tid][KK - 1]) {
                    int p = KK - 1;
                    while (p > 0 && listK[tid][p - 1] > key) {
                        listK[tid][p] = listK[tid][p - 1];
                        --p;
                    }
                    listK[tid][p] = key;
                }
            }
            pendCnt[tid] = 0;
        }
        __syncthreads();
    }

    if (tid < ROWS) {
        const int n = row0 + tid;
        int* o0 = out + ((size_t)(0 * NB + b) * NPTS + n) * KOUT;
        int* o1 = out + ((size_t)(1 * NB + b) * NPTS + n) * KOUT;
        #pragma unroll
        for (int k = 0; k < KOUT; ++k) {
            o0[k] = (int)(unsigned)(listK[tid][2 * k] & 0xFFFFFFFFULL);
            o1[k] = n;
        }
    }
}

extern "C" void kernel_launch(void* const* d_in, const int* in_sizes, int n_in,
                              void* d_out, int out_size, void* d_ws, size_t ws_size,
                              hipStream_t stream) {
    const float* x = (const float*)d_in[0];
    int* out = (int*)d_out;
    float* pts = (float*)d_ws;                                  // B*C*N fp32 = 8 MB
    float* sq  = (float*)d_ws + (size_t)NB * NC * NPTS;         // B*N fp32

    normalize_kernel<<<(NB * NPTS + 255) / 256, 256, 0, stream>>>(x, pts, sq);
    knn_kernel<<<NB * (NPTS / ROWS), 256, 0, stream>>>(pts, sq, out);
}